// Round 11
// baseline (248.745 us; speedup 1.0000x reference)
//
#include <hip/hip_runtime.h>
#include <cmath>

#define H     256
#define H3    768
#define L     32
#define STEPS 20
#define VOUT  74
#define NP    16            // participant WGs (elected, same XCD)
#define NB    128           // launched WGs (pigeonhole: some XCD gets >=16)
#define HW    16            // h rows per WG
#define ROWS  48            // gh rows per WG (3 gates x 16)

// ---- workspace layout (32-bit word offsets) ----
#define WS_CNT   0                        // int cnt[8] per-XCD arrival tickets
#define WS_WIN   8                        // int winner (-1 until elected)
#define WS_HX    16                       // u64 [2][256] packed (val<<32|tag)
// tags are NEVER pre-zeroed: wanted tags are 1..52; stale finals (>=33) and
// 0xAA poison can't alias the first-wanted tag per word (1 or 2); later wants
// are protected by per-location coherence once a fresh tag was observed.

__device__ __forceinline__ float sigmoidf_(float x) {
    return 1.0f / (1.0f + expf(-x));
}

// global gh-row for local row lr (0..47) of role w:
// lr 0..15 -> r rows j, 16..31 -> z rows H+j, 32..47 -> n rows 2H+j
__device__ __forceinline__ int growf(int w, int lr) {
    int j = w * HW + (lr & 15);
    return (lr < 16) ? j : (lr < 32 ? H + j : 2 * H + j);
}

// Tiny prep: reset election state only (9 words). Tags need no reset (above).
__global__ void prep(float* __restrict__ ws) {
    if (threadIdx.x < 16)
        ((int*)ws)[threadIdx.x] = (threadIdx.x == WS_WIN) ? -1 : 0;
}

// Sequential phase: 16 elected same-XCD WGs. Whh + fc_W in registers,
// gi slices computed in-WG into LDS, h exchanged via packed tagged 8B
// agent-scope atomics (R5-proven protocol, round-trip optimal).
__global__ __launch_bounds__(256, 1) void gru_seq(
        const int*   __restrict__ enc_input,
        const float* __restrict__ enc_emb, const float* __restrict__ enc_Wih,
        const float* __restrict__ enc_bih,
        const float* __restrict__ dec_emb, const float* __restrict__ dec_Wih,
        const float* __restrict__ dec_bih,
        const float* __restrict__ enc_Whh, const float* __restrict__ enc_bhh,
        const float* __restrict__ dec_Whh, const float* __restrict__ dec_bhh,
        const float* __restrict__ fc_W,    const float* __restrict__ fc_b,
        float* __restrict__ ws, int* __restrict__ out) {
    __shared__ __align__(16) float hl[1040];   // 4 bank-shifted copies (stride 260)
    __shared__ float fb[VOUT];
    __shared__ float gh_l[ROWS];
    __shared__ float egi_l[L * ROWS];          // [32][48]
    __shared__ float dgi_l[VOUT * ROWS];       // [74][48]
    __shared__ float log_l[VOUT];
    __shared__ int   s_tok, s_done, s_role;

    const int t = threadIdx.x;

    // ---- election: first XCD to collect NP workgroups wins ----
    if (t == 0) {
        int xcd;
        asm volatile("s_getreg_b32 %0, hwreg(HW_REG_XCC_ID)" : "=s"(xcd));
        xcd &= 7;
        int* cnt = (int*)ws + WS_CNT;
        int* win = (int*)ws + WS_WIN;
        int rank = __hip_atomic_fetch_add(&cnt[xcd], 1, __ATOMIC_RELAXED,
                                          __HIP_MEMORY_SCOPE_AGENT);
        if (rank == NP - 1) {
            int expect = -1;
            __hip_atomic_compare_exchange_strong(win, &expect, xcd,
                __ATOMIC_RELAXED, __ATOMIC_RELAXED, __HIP_MEMORY_SCOPE_AGENT);
        }
        int wv;
        while ((wv = __hip_atomic_load(win, __ATOMIC_RELAXED,
                                       __HIP_MEMORY_SCOPE_AGENT)) < 0)
            __builtin_amdgcn_s_sleep(2);
        s_role = (wv == xcd && rank < NP) ? rank : -1;
        s_done = 0; s_tok = 2;                  // BOS=2
    }
    __syncthreads();
    const int w = s_role;
    if (w < 0) return;                          // non-participant

    unsigned long long* hx = (unsigned long long*)((int*)ws + WS_HX);

    // ---- one-time staging ----
    if (w == 0 && t < STEPS) out[t] = 0;
    if (t < VOUT) fb[t] = fc_b[t];
    for (int k = t; k < 1040; k += 256) hl[k] = 0.f;   // h^0 = 0 (skip s=0 poll)

    // gi slices computed in-WG: thread (glr = t>>2, gp = t&3), 4 threads/row.
    {
        const int glr = t >> 2;                 // 0..63, valid < 48
        const int gp  = t & 3;
        if (glr < ROWS) {
            const int gg = growf(w, glr);
            float4 wI[16];
            // encoder items
            {
                const float* wp = enc_Wih + gg * H + gp * 64;
                #pragma unroll
                for (int i = 0; i < 16; ++i) wI[i] = *(const float4*)(wp + 4 * i);
                float bi = enc_bih[gg];
                for (int item = 0; item < L; ++item) {
                    const float* x = enc_emb + enc_input[item] * H + gp * 64;
                    float a0 = 0.f, a1 = 0.f;
                    #pragma unroll
                    for (int i = 0; i < 16; i += 2) {
                        float4 xa = *(const float4*)(x + 4 * i);
                        float4 xb = *(const float4*)(x + 4 * i + 4);
                        a0 = fmaf(wI[i].x, xa.x, fmaf(wI[i].y, xa.y,
                             fmaf(wI[i].z, xa.z, fmaf(wI[i].w, xa.w, a0))));
                        a1 = fmaf(wI[i+1].x, xb.x, fmaf(wI[i+1].y, xb.y,
                             fmaf(wI[i+1].z, xb.z, fmaf(wI[i+1].w, xb.w, a1))));
                    }
                    float a = a0 + a1;
                    a += __shfl_xor(a, 1); a += __shfl_xor(a, 2);
                    if (gp == 0) egi_l[item * ROWS + glr] = a + bi;
                }
            }
            // decoder candidate tokens
            {
                const float* wp = dec_Wih + gg * H + gp * 64;
                #pragma unroll
                for (int i = 0; i < 16; ++i) wI[i] = *(const float4*)(wp + 4 * i);
                float bi = dec_bih[gg];
                for (int item = 0; item < VOUT; ++item) {
                    const float* x = dec_emb + item * H + gp * 64;
                    float a0 = 0.f, a1 = 0.f;
                    #pragma unroll
                    for (int i = 0; i < 16; i += 2) {
                        float4 xa = *(const float4*)(x + 4 * i);
                        float4 xb = *(const float4*)(x + 4 * i + 4);
                        a0 = fmaf(wI[i].x, xa.x, fmaf(wI[i].y, xa.y,
                             fmaf(wI[i].z, xa.z, fmaf(wI[i].w, xa.w, a0))));
                        a1 = fmaf(wI[i+1].x, xb.x, fmaf(wI[i+1].y, xb.y,
                             fmaf(wI[i+1].z, xb.z, fmaf(wI[i+1].w, xb.w, a1))));
                    }
                    float a = a0 + a1;
                    a += __shfl_xor(a, 1); a += __shfl_xor(a, 2);
                    if (gp == 0) dgi_l[item * ROWS + glr] = a + bi;
                }
            }
        }
    }

    // Whh slices (matvec workers t in [64,256): 4 threads per gh row)
    const int m  = t - 64;
    const int p  = t & 3;                 // k-chunk (64 floats each)
    const int lr = (t >= 64) ? (m >> 2) : 0;
    const int g  = growf(w, lr);
    float4 wE[16], wD[16];
    float bhhE = 0.f, bhhD = 0.f;
    if (t >= 64) {
        const float* eb = enc_Whh + g * H + p * 64;
        const float* db = dec_Whh + g * H + p * 64;
        #pragma unroll
        for (int i = 0; i < 16; ++i) {
            wE[i] = *(const float4*)(eb + 4 * i);
            wD[i] = *(const float4*)(db + 4 * i);
        }
        if (p == 0) { bhhE = enc_bhh[g]; bhhD = dec_bhh[g]; }
    }

    // fc_W in registers: primary row t>>2, chunk t&3; secondary 64+(t>>2) for t<40
    const int rF = t >> 2;
    float4 wF[16], wF2[16];
    {
        const float* fp = fc_W + rF * H + p * 64;
        #pragma unroll
        for (int i = 0; i < 16; ++i) wF[i] = *(const float4*)(fp + 4 * i);
        if (t < 40) {
            const float* fp2 = fc_W + (64 + rF) * H + p * 64;
            #pragma unroll
            for (int i = 0; i < 16; ++i) wF2[i] = *(const float4*)(fp2 + 4 * i);
        }
    }

    int tok = 2;  // BOS
    for (int s = 0; s <= L + STEPS; ++s) {      // 0..52
        // ---- wait for h^(s) (s>0): thread t polls its own packed word ----
        if (s > 0) {
            const unsigned long long* src = hx + (s & 1) * H + t;
            unsigned long long pk = __hip_atomic_load(src, __ATOMIC_RELAXED,
                                                      __HIP_MEMORY_SCOPE_AGENT);
            while ((unsigned)pk != (unsigned)s) {
                __builtin_amdgcn_s_sleep(1);
                pk = __hip_atomic_load(src, __ATOMIC_RELAXED,
                                       __HIP_MEMORY_SCOPE_AGENT);
            }
            float hv = __uint_as_float((unsigned)(pk >> 32));
            hl[t] = hv; hl[260 + t] = hv; hl[520 + t] = hv; hl[780 + t] = hv;
        }
        __syncthreads();   // s=0: also covers staging writes (hl zeros, gi)

        const bool dec_out = (s >= L + 1);
        if (dec_out) {
            // ---- logits from registers (2 independent FMA chains) ----
            const float* hb2 = hl + p * 324;
            float a0 = 0.f, a1 = 0.f;
            #pragma unroll
            for (int i = 0; i < 16; i += 2) {
                float4 h4a = *(const float4*)(hb2 + 4 * i);
                float4 h4b = *(const float4*)(hb2 + 4 * i + 4);
                a0 = fmaf(wF[i].x, h4a.x, fmaf(wF[i].y, h4a.y,
                      fmaf(wF[i].z, h4a.z, fmaf(wF[i].w, h4a.w, a0))));
                a1 = fmaf(wF[i+1].x, h4b.x, fmaf(wF[i+1].y, h4b.y,
                      fmaf(wF[i+1].z, h4b.z, fmaf(wF[i+1].w, h4b.w, a1))));
            }
            float a = a0 + a1;
            a += __shfl_xor(a, 1); a += __shfl_xor(a, 2);
            if (p == 0) log_l[rF] = a + fb[rF];
            if (t < 40) {
                float b0 = 0.f, b1 = 0.f;
                #pragma unroll
                for (int i = 0; i < 16; i += 2) {
                    float4 h4a = *(const float4*)(hb2 + 4 * i);
                    float4 h4b = *(const float4*)(hb2 + 4 * i + 4);
                    b0 = fmaf(wF2[i].x, h4a.x, fmaf(wF2[i].y, h4a.y,
                          fmaf(wF2[i].z, h4a.z, fmaf(wF2[i].w, h4a.w, b0))));
                    b1 = fmaf(wF2[i+1].x, h4b.x, fmaf(wF2[i+1].y, h4b.y,
                          fmaf(wF2[i+1].z, h4b.z, fmaf(wF2[i+1].w, h4b.w, b1))));
                }
                float a2 = b0 + b1;
                a2 += __shfl_xor(a2, 1); a2 += __shfl_xor(a2, 2);
                if (p == 0) log_l[64 + rF] = a2 + fb[64 + rF];
            }
            __syncthreads();
        }

        // ---- wave0: argmax  ||  waves1-3: GRU matvec (tok-independent) ----
        if (t < 64) {
            if (dec_out) {
                float v = log_l[t]; int bi = t;
                if (t < VOUT - 64) {
                    float v2 = log_l[64 + t];
                    if (v2 > v) { v = v2; bi = 64 + t; }
                }
                #pragma unroll
                for (int mm = 1; mm < 64; mm <<= 1) {
                    float ov = __shfl_xor(v, mm);
                    int   ob = __shfl_xor(bi, mm);
                    if (ov > v || (ov == v && ob < bi)) { v = ov; bi = ob; }
                }
                if (t == 0) {
                    bool eos = (bi == 3);                    // EOS=3
                    if (w == 0 && !eos) out[s - (L + 1)] = bi;
                    s_tok = bi;
                    if (eos) s_done = 1;
                }
            }
        } else {
            float acc0 = (s < L) ? bhhE : bhhD, acc1 = 0.f;
            const float* hb = hl + p * 324;      // copy p, k-offset p*64
            if (s < L) {
                #pragma unroll
                for (int i = 0; i < 16; i += 2) {
                    float4 h4a = *(const float4*)(hb + 4 * i);
                    float4 h4b = *(const float4*)(hb + 4 * i + 4);
                    acc0 = fmaf(wE[i].x, h4a.x, fmaf(wE[i].y, h4a.y,
                           fmaf(wE[i].z, h4a.z, fmaf(wE[i].w, h4a.w, acc0))));
                    acc1 = fmaf(wE[i+1].x, h4b.x, fmaf(wE[i+1].y, h4b.y,
                           fmaf(wE[i+1].z, h4b.z, fmaf(wE[i+1].w, h4b.w, acc1))));
                }
            } else {
                #pragma unroll
                for (int i = 0; i < 16; i += 2) {
                    float4 h4a = *(const float4*)(hb + 4 * i);
                    float4 h4b = *(const float4*)(hb + 4 * i + 4);
                    acc0 = fmaf(wD[i].x, h4a.x, fmaf(wD[i].y, h4a.y,
                           fmaf(wD[i].z, h4a.z, fmaf(wD[i].w, h4a.w, acc0))));
                    acc1 = fmaf(wD[i+1].x, h4b.x, fmaf(wD[i+1].y, h4b.y,
                           fmaf(wD[i+1].z, h4b.z, fmaf(wD[i+1].w, h4b.w, acc1))));
                }
            }
            float acc = acc0 + acc1;
            acc += __shfl_xor(acc, 1);
            acc += __shfl_xor(acc, 2);
            if (p == 0) gh_l[m >> 2] = acc;
        }
        __syncthreads();

        if (dec_out) {
            tok = s_tok;
            if (s_done || s == L + STEPS) break;
        }

        // ---- gates -> h^(s+1) slice: ONE packed 8B tagged store ----
        if (t < HW) {
            const float* gi = (s < L) ? (egi_l + s * ROWS) : (dgi_l + tok * ROWS);
            float r = sigmoidf_(gi[t]      + gh_l[t]);
            float z = sigmoidf_(gi[16 + t] + gh_l[16 + t]);
            float n = tanhf    (gi[32 + t] + r * gh_l[32 + t]);
            float hn = (1.f - z) * n + z * hl[w * HW + t];
            unsigned long long pk =
                ((unsigned long long)__float_as_uint(hn) << 32) |
                (unsigned)(s + 1);
            __hip_atomic_store(hx + ((s + 1) & 1) * H + w * HW + t, pk,
                               __ATOMIC_RELAXED, __HIP_MEMORY_SCOPE_AGENT);
        }
        // no trailing barrier: cross-WG ordering rides on the tagged word;
        // intra-WG LDS hazards are covered by the per-iteration barriers.
    }
}

extern "C" void kernel_launch(void* const* d_in, const int* in_sizes, int n_in,
                              void* d_out, int out_size, void* d_ws, size_t ws_size,
                              hipStream_t stream) {
    const int*   enc_input = (const int*)  d_in[0];
    const float* enc_emb   = (const float*)d_in[1];
    const float* enc_Wih   = (const float*)d_in[2];
    const float* enc_Whh   = (const float*)d_in[3];
    const float* enc_bih   = (const float*)d_in[4];
    const float* enc_bhh   = (const float*)d_in[5];
    const float* dec_emb   = (const float*)d_in[6];
    const float* dec_Wih   = (const float*)d_in[7];
    const float* dec_Whh   = (const float*)d_in[8];
    const float* dec_bih   = (const float*)d_in[9];
    const float* dec_bhh   = (const float*)d_in[10];
    const float* fc_W      = (const float*)d_in[11];
    const float* fc_b      = (const float*)d_in[12];
    float* ws  = (float*)d_ws;
    int*  outp = (int*)d_out;

    hipLaunchKernelGGL(prep, dim3(1), dim3(64), 0, stream, ws);
    hipLaunchKernelGGL(gru_seq, dim3(NB), dim3(256), 0, stream,
                       enc_input, enc_emb, enc_Wih, enc_bih,
                       dec_emb, dec_Wih, dec_bih,
                       enc_Whh, enc_bhh, dec_Whh, dec_bhh, fc_W, fc_b,
                       ws, outp);
}

// Round 12
// 118.001 us; speedup vs baseline: 2.1080x; 2.1080x over previous
//
#include <hip/hip_runtime.h>
#include <cmath>

#define H     256
#define H3    768
#define L     32
#define STEPS 20
#define VOUT  74
#define NP    16            // participant WGs (elected, same XCD)
#define NB    128           // launched WGs (pigeonhole: some XCD gets >=16)
#define HW    16            // h rows per WG
#define ROWS  48            // gh rows per WG (3 gates x 16)

// ---- workspace layout (32-bit word offsets) ----
#define WS_CNT   0                        // int cnt[8] per-XCD arrival tickets
#define WS_WIN   8                        // int winner (-1 until elected)
#define WS_HX    16                       // u64 [2][256] packed (val<<32|tag)
#define WS_EGI   1040                     // float [NP][L][48]   blocked by consumer
#define WS_DGI   (1040 + NP * L * ROWS)   // float [NP][VOUT][48] -> 25616
// Tags are NEVER pre-zeroed (proven replay-safe by R11): wanted tags are 1..52;
// a word's stale final tag from a prior replay is >=32, poison is 0xAAAAAAAA,
// fresh-alloc is 0 -- none alias the first-wanted tag (1 or 2); later wants are
// protected by per-location coherence once a fresh tag was observed.

__device__ __forceinline__ float sigmoidf_(float x) {
    return 1.0f / (1.0f + expf(-x));
}

// global gh-row for local row lr (0..47) of role w:
// lr 0..15 -> r rows j, 16..31 -> z rows H+j, 32..47 -> n rows 2H+j
__device__ __forceinline__ int growf(int w, int lr) {
    int j = w * HW + (lr & 15);
    return (lr < 16) ? j : (lr < 32 ? H + j : 2 * H + j);
}

// Prep: reset election words only; precompute input-side gate projections
// into [role][item][48]. One wave per Wih row, reused across 8 items.
__global__ void prep(const int*   __restrict__ enc_input,
                     const float* __restrict__ enc_emb,
                     const float* __restrict__ encWih,
                     const float* __restrict__ enc_bih,
                     const float* __restrict__ dec_emb,
                     const float* __restrict__ decWih,
                     const float* __restrict__ dec_bih,
                     float* __restrict__ ws) {
    if (blockIdx.x == 0 && threadIdx.x < 16)
        ((int*)ws)[threadIdx.x] = (threadIdx.x == WS_WIN) ? -1 : 0;

    int wid  = blockIdx.x * 4 + (threadIdx.x >> 6);
    int lane = threadIdx.x & 63;

    int j, i0, nIt; const float* W; const float* b; bool isEnc;
    if (wid < 3072) {                 // enc: 768 rows x 4 item-groups of 8
        j = wid >> 2; i0 = (wid & 3) * 8; nIt = 8;
        W = encWih; b = enc_bih; isEnc = true;
    } else {                          // dec: 768 rows x 10 item-groups of 8
        int w2 = wid - 3072;
        if (w2 >= 7680) return;
        j = w2 / 10; i0 = (w2 % 10) * 8;
        nIt = (VOUT - i0 < 8) ? (VOUT - i0) : 8;
        W = decWih; b = dec_bih; isEnc = false;
    }
    float4 wv = ((const float4*)(W + j * H))[lane];
    float bj = b[j];
    int wOwn = (j & 255) >> 4;                 // consumer role
    int lr   = (j >> 8) * 16 + (j & 15);       // local row within role

    for (int ii = 0; ii < nIt; ++ii) {
        int item = i0 + ii;
        const float* x = isEnc ? (enc_emb + enc_input[item] * H)
                               : (dec_emb + item * H);
        float4 xv = ((const float4*)x)[lane];
        float s = fmaf(wv.x, xv.x, fmaf(wv.y, xv.y, fmaf(wv.z, xv.z, wv.w * xv.w)));
        #pragma unroll
        for (int m = 1; m < 64; m <<= 1) s += __shfl_xor(s, m);
        if (lane == 0) {
            float* op = isEnc
                ? ws + WS_EGI + (wOwn * L + item) * ROWS + lr
                : ws + WS_DGI + (wOwn * VOUT + item) * ROWS + lr;
            *op = s + bj;
        }
    }
}

// Sequential phase: 16 elected same-XCD WGs. Whh + fc_W in registers,
// gi slices in LDS, h exchanged via packed tagged 8B agent-scope atomics
// (R5-proven protocol; round-trip-optimal: data arrival IS the signal).
__global__ __launch_bounds__(256, 1) void gru_seq(
        const float* __restrict__ enc_Whh, const float* __restrict__ enc_bhh,
        const float* __restrict__ dec_Whh, const float* __restrict__ dec_bhh,
        const float* __restrict__ fc_W,    const float* __restrict__ fc_b,
        float* __restrict__ ws, int* __restrict__ out) {
    __shared__ __align__(16) float hl[1040];   // 4 bank-shifted copies (stride 260)
    __shared__ float fb[VOUT];
    __shared__ float gh_l[ROWS];
    __shared__ float egi_l[L * ROWS];          // [32][48]
    __shared__ float dgi_l[VOUT * ROWS];       // [74][48]
    __shared__ float log_l[VOUT];
    __shared__ int   s_tok, s_done, s_role;

    const int t = threadIdx.x;

    // ---- election: first XCD to collect NP workgroups wins ----
    if (t == 0) {
        int xcd;
        asm volatile("s_getreg_b32 %0, hwreg(HW_REG_XCC_ID)" : "=s"(xcd));
        xcd &= 7;
        int* cnt = (int*)ws + WS_CNT;
        int* win = (int*)ws + WS_WIN;
        int rank = __hip_atomic_fetch_add(&cnt[xcd], 1, __ATOMIC_RELAXED,
                                          __HIP_MEMORY_SCOPE_AGENT);
        if (rank == NP - 1) {
            int expect = -1;
            __hip_atomic_compare_exchange_strong(win, &expect, xcd,
                __ATOMIC_RELAXED, __ATOMIC_RELAXED, __HIP_MEMORY_SCOPE_AGENT);
        }
        int wv;
        while ((wv = __hip_atomic_load(win, __ATOMIC_RELAXED,
                                       __HIP_MEMORY_SCOPE_AGENT)) < 0)
            __builtin_amdgcn_s_sleep(2);
        s_role = (wv == xcd && rank < NP) ? rank : -1;
        s_done = 0; s_tok = 2;                  // BOS=2
    }
    __syncthreads();
    const int w = s_role;
    if (w < 0) return;                          // non-participant

    unsigned long long* hx = (unsigned long long*)((int*)ws + WS_HX);

    // ---- one-time staging (coalesced: blocked gi layout) ----
    if (w == 0 && t < STEPS) out[t] = 0;
    if (t < VOUT) fb[t] = fc_b[t];
    for (int k = t; k < 1040; k += 256) hl[k] = 0.f;   // h^0 = 0: skip s=0 poll
    for (int idx = t; idx < L * ROWS; idx += 256)
        egi_l[idx] = ws[WS_EGI + w * (L * ROWS) + idx];
    for (int idx = t; idx < VOUT * ROWS; idx += 256)
        dgi_l[idx] = ws[WS_DGI + w * (VOUT * ROWS) + idx];

    // Whh slices (matvec workers t in [64,256): 4 threads per gh row)
    const int m  = t - 64;
    const int p  = t & 3;                 // k-chunk (64 floats each)
    const int lr = (t >= 64) ? (m >> 2) : 0;
    const int g  = growf(w, lr);
    float4 wE[16], wD[16];
    float bhhE = 0.f, bhhD = 0.f;
    if (t >= 64) {
        const float* eb = enc_Whh + g * H + p * 64;
        const float* db = dec_Whh + g * H + p * 64;
        #pragma unroll
        for (int i = 0; i < 16; ++i) {
            wE[i] = *(const float4*)(eb + 4 * i);
            wD[i] = *(const float4*)(db + 4 * i);
        }
        if (p == 0) { bhhE = enc_bhh[g]; bhhD = dec_bhh[g]; }
    }

    // fc_W in registers: primary row t>>2, chunk t&3; secondary 64+(t>>2) for t<40
    const int rF = t >> 2;
    float4 wF[16], wF2[16];
    {
        const float* fp = fc_W + rF * H + p * 64;
        #pragma unroll
        for (int i = 0; i < 16; ++i) wF[i] = *(const float4*)(fp + 4 * i);
        if (t < 40) {
            const float* fp2 = fc_W + (64 + rF) * H + p * 64;
            #pragma unroll
            for (int i = 0; i < 16; ++i) wF2[i] = *(const float4*)(fp2 + 4 * i);
        }
    }

    int tok = 2;  // BOS
    for (int s = 0; s <= L + STEPS; ++s) {      // 0..52
        // ---- wait for h^(s) (s>0): thread t polls its own packed word ----
        if (s > 0) {
            const unsigned long long* src = hx + (s & 1) * H + t;
            unsigned long long pk = __hip_atomic_load(src, __ATOMIC_RELAXED,
                                                      __HIP_MEMORY_SCOPE_AGENT);
            while ((unsigned)pk != (unsigned)s) {
                __builtin_amdgcn_s_sleep(1);
                pk = __hip_atomic_load(src, __ATOMIC_RELAXED,
                                       __HIP_MEMORY_SCOPE_AGENT);
            }
            float hv = __uint_as_float((unsigned)(pk >> 32));
            hl[t] = hv; hl[260 + t] = hv; hl[520 + t] = hv; hl[780 + t] = hv;
        }
        __syncthreads();   // s=0: also orders staging writes (hl zeros, gi)

        const bool dec_out = (s >= L + 1);
        if (dec_out) {
            // ---- logits from registers (2 independent FMA chains) ----
            const float* hb2 = hl + p * 324;
            float a0 = 0.f, a1 = 0.f;
            #pragma unroll
            for (int i = 0; i < 16; i += 2) {
                float4 h4a = *(const float4*)(hb2 + 4 * i);
                float4 h4b = *(const float4*)(hb2 + 4 * i + 4);
                a0 = fmaf(wF[i].x, h4a.x, fmaf(wF[i].y, h4a.y,
                      fmaf(wF[i].z, h4a.z, fmaf(wF[i].w, h4a.w, a0))));
                a1 = fmaf(wF[i+1].x, h4b.x, fmaf(wF[i+1].y, h4b.y,
                      fmaf(wF[i+1].z, h4b.z, fmaf(wF[i+1].w, h4b.w, a1))));
            }
            float a = a0 + a1;
            a += __shfl_xor(a, 1); a += __shfl_xor(a, 2);
            if (p == 0) log_l[rF] = a + fb[rF];
            if (t < 40) {
                float b0 = 0.f, b1 = 0.f;
                #pragma unroll
                for (int i = 0; i < 16; i += 2) {
                    float4 h4a = *(const float4*)(hb2 + 4 * i);
                    float4 h4b = *(const float4*)(hb2 + 4 * i + 4);
                    b0 = fmaf(wF2[i].x, h4a.x, fmaf(wF2[i].y, h4a.y,
                          fmaf(wF2[i].z, h4a.z, fmaf(wF2[i].w, h4a.w, b0))));
                    b1 = fmaf(wF2[i+1].x, h4b.x, fmaf(wF2[i+1].y, h4b.y,
                          fmaf(wF2[i+1].z, h4b.z, fmaf(wF2[i+1].w, h4b.w, b1))));
                }
                float a2 = b0 + b1;
                a2 += __shfl_xor(a2, 1); a2 += __shfl_xor(a2, 2);
                if (p == 0) log_l[64 + rF] = a2 + fb[64 + rF];
            }
            __syncthreads();
        }

        // ---- wave0: argmax  ||  waves1-3: GRU matvec (tok-independent) ----
        if (t < 64) {
            if (dec_out) {
                float v = log_l[t]; int bi = t;
                if (t < VOUT - 64) {
                    float v2 = log_l[64 + t];
                    if (v2 > v) { v = v2; bi = 64 + t; }
                }
                #pragma unroll
                for (int mm = 1; mm < 64; mm <<= 1) {
                    float ov = __shfl_xor(v, mm);
                    int   ob = __shfl_xor(bi, mm);
                    if (ov > v || (ov == v && ob < bi)) { v = ov; bi = ob; }
                }
                if (t == 0) {
                    bool eos = (bi == 3);                    // EOS=3
                    if (w == 0 && !eos) out[s - (L + 1)] = bi;
                    s_tok = bi;
                    if (eos) s_done = 1;
                }
            }
        } else {
            float acc0 = (s < L) ? bhhE : bhhD, acc1 = 0.f;
            const float* hb = hl + p * 324;      // copy p, k-offset p*64
            if (s < L) {
                #pragma unroll
                for (int i = 0; i < 16; i += 2) {
                    float4 h4a = *(const float4*)(hb + 4 * i);
                    float4 h4b = *(const float4*)(hb + 4 * i + 4);
                    acc0 = fmaf(wE[i].x, h4a.x, fmaf(wE[i].y, h4a.y,
                           fmaf(wE[i].z, h4a.z, fmaf(wE[i].w, h4a.w, acc0))));
                    acc1 = fmaf(wE[i+1].x, h4b.x, fmaf(wE[i+1].y, h4b.y,
                           fmaf(wE[i+1].z, h4b.z, fmaf(wE[i+1].w, h4b.w, acc1))));
                }
            } else {
                #pragma unroll
                for (int i = 0; i < 16; i += 2) {
                    float4 h4a = *(const float4*)(hb + 4 * i);
                    float4 h4b = *(const float4*)(hb + 4 * i + 4);
                    acc0 = fmaf(wD[i].x, h4a.x, fmaf(wD[i].y, h4a.y,
                           fmaf(wD[i].z, h4a.z, fmaf(wD[i].w, h4a.w, acc0))));
                    acc1 = fmaf(wD[i+1].x, h4b.x, fmaf(wD[i+1].y, h4b.y,
                           fmaf(wD[i+1].z, h4b.z, fmaf(wD[i+1].w, h4b.w, acc1))));
                }
            }
            float acc = acc0 + acc1;
            acc += __shfl_xor(acc, 1);
            acc += __shfl_xor(acc, 2);
            if (p == 0) gh_l[m >> 2] = acc;
        }
        __syncthreads();

        if (dec_out) {
            tok = s_tok;
            if (s_done || s == L + STEPS) break;
        }

        // ---- gates -> h^(s+1) slice: ONE packed 8B tagged store ----
        if (t < HW) {
            const float* gi = (s < L) ? (egi_l + s * ROWS) : (dgi_l + tok * ROWS);
            float r = sigmoidf_(gi[t]      + gh_l[t]);
            float z = sigmoidf_(gi[16 + t] + gh_l[16 + t]);
            float n = tanhf    (gi[32 + t] + r * gh_l[32 + t]);
            float hn = (1.f - z) * n + z * hl[w * HW + t];
            unsigned long long pk =
                ((unsigned long long)__float_as_uint(hn) << 32) |
                (unsigned)(s + 1);
            __hip_atomic_store(hx + ((s + 1) & 1) * H + w * HW + t, pk,
                               __ATOMIC_RELAXED, __HIP_MEMORY_SCOPE_AGENT);
        }
        // no trailing barrier: cross-WG ordering rides on the tagged word;
        // intra-WG LDS hazards are covered by the per-iteration barriers.
    }
}

extern "C" void kernel_launch(void* const* d_in, const int* in_sizes, int n_in,
                              void* d_out, int out_size, void* d_ws, size_t ws_size,
                              hipStream_t stream) {
    const int*   enc_input = (const int*)  d_in[0];
    const float* enc_emb   = (const float*)d_in[1];
    const float* enc_Wih   = (const float*)d_in[2];
    const float* enc_Whh   = (const float*)d_in[3];
    const float* enc_bih   = (const float*)d_in[4];
    const float* enc_bhh   = (const float*)d_in[5];
    const float* dec_emb   = (const float*)d_in[6];
    const float* dec_Wih   = (const float*)d_in[7];
    const float* dec_Whh   = (const float*)d_in[8];
    const float* dec_bih   = (const float*)d_in[9];
    const float* dec_bhh   = (const float*)d_in[10];
    const float* fc_W      = (const float*)d_in[11];
    const float* fc_b      = (const float*)d_in[12];
    float* ws  = (float*)d_ws;
    int*  outp = (int*)d_out;

    // prep: 3072 enc + 7680 dec wave-tasks, 4 waves/block
    hipLaunchKernelGGL(prep, dim3(2688), dim3(256), 0, stream,
                       enc_input, enc_emb, enc_Wih, enc_bih,
                       dec_emb, dec_Wih, dec_bih, ws);
    hipLaunchKernelGGL(gru_seq, dim3(NB), dim3(256), 0, stream,
                       enc_Whh, enc_bhh, dec_Whh, dec_bhh, fc_W, fc_b,
                       ws, outp);
}